// Round 17
// baseline (288.810 us; speedup 1.0000x reference)
//
#include <hip/hip_runtime.h>

#define TPB 256
#define HID 128
#define IN_C 4
#define SLOT_C 32          // per-node slot capacity; Poisson(16): P(deg>32)~1e-4,
                           // ~10 overflow nodes @ n=1e5 -> ovf list handles them.

typedef __attribute__((ext_vector_type(8))) short bf16x8;   // 8 bf16 = 4 VGPRs
typedef __attribute__((ext_vector_type(4))) float f32x4;

union FragU { uint4 u; bf16x8 b; };

// bf16 helpers: pack with RNE, unpack with shift (values finite, no NaN)
__device__ __forceinline__ unsigned f2bf(float f) {
    unsigned u = __float_as_uint(f);
    return (u + 0x7fffu + ((u >> 16) & 1u)) >> 16;
}
__device__ __forceinline__ float bf_lo(unsigned u) { return __uint_as_float(u << 16); }
__device__ __forceinline__ float bf_hi(unsigned u) { return __uint_as_float(u & 0xffff0000u); }

// ---------------------------------------------------------------------------
// K0: fused prep — role by blockIdx: [0,nbA) zero cursor/out; [nbA,nbA+64)
// w2frag swizzle; last block: per-graph counts + ovf_cnt=0.
__global__ void k_prep(int* cursor, float* out, int n, int outsz,
                       const float* __restrict__ W2, unsigned short* w2f,
                       const int* __restrict__ batch, int* cnt, int bg,
                       int* ovf_cnt) {
    int nbA = (n + TPB - 1) / TPB;
    int b = blockIdx.x;
    if (b < nbA) {
        int i = b * TPB + threadIdx.x;
        if (i < n) cursor[i] = 0;
        if (i < outsz) out[i] = 0.0f;
    } else if (b < nbA + 64) {
        int i = (b - nbA) * TPB + threadIdx.x;   // 0..16383
        if (i < HID * HID) {
            int j = i & 7, frag = i >> 3;
            int lane = frag & 63, blk = frag >> 6;       // blk = kk*8 + nt
            int kk = blk >> 3, nt = blk & 7;
            int quad = lane >> 4, nloc = lane & 15;
            int k = kk * 32 + quad * 8 + j;
            int c = nt * 16 + nloc;
            w2f[i] = (unsigned short)f2bf(W2[k * HID + c]);
        }
    } else {
        int g = threadIdx.x;
        if (g == 0) *ovf_cnt = 0;
        if (g < bg) {
            int lo0 = 0, hi0 = n;
            while (lo0 < hi0) { int m = (lo0 + hi0) >> 1; if (batch[m] < g) lo0 = m + 1; else hi0 = m; }
            int lo1 = lo0, hi1 = n;
            while (lo1 < hi1) { int m = (lo1 + hi1) >> 1; if (batch[m] < g + 1) lo1 = m + 1; else hi1 = m; }
            cnt[g] = lo1 - lo0;
        }
    }
}

// K1: direct bucket sort, XCD-localized (8 filtered passes).
// dst/src read NON-TEMPORALLY: the one-shot streams must not evict the
// slot slice (1.6 MB/XCD) from L2 — R16 showed WRITE 79 MB (no merge)
// because normal streaming loads thrashed the slot lines between the ~16
// partial writes each 64B line needs.
__global__ void k_bucket(const int* __restrict__ src, const int* __restrict__ dst,
                         int* cursor, int* slots, int* ovf, int* ovf_cnt,
                         int e, int n) {
    int pass = blockIdx.x & 7;
    int i = (blockIdx.x >> 3) * blockDim.x + threadIdx.x;
    if (i >= e) return;
    int rlo = (int)(((long)n * pass) >> 3);
    int rhi = (int)(((long)n * (pass + 1)) >> 3);
    int d = __builtin_nontemporal_load(dst + i);
    if (d >= rlo && d < rhi) {
        int s = __builtin_nontemporal_load(src + i);
        int p = atomicAdd(&cursor[d], 1);
        if (p < SLOT_C) {
            slots[d * SLOT_C + p] = s;
        } else {                                  // rare (P~1e-4 per node)
            int o = atomicAdd(ovf_cnt, 1);
            ovf[2 * o] = s;
            ovf[2 * o + 1] = d;
        }
    }
}

// K2: dinv = rsqrt(deg + 1)  (deg = cursor)
__global__ void k_dinv(const int* __restrict__ cursor, float* dinv, int n) {
    int i = blockIdx.x * blockDim.x + threadIdx.x;
    if (i < n) dinv[i] = rsqrtf((float)cursor[i] + 1.0f);
}

// K6: layer-1 propagation as gather on raw 4-channel x; unroll x4 for MLP.
// Overflow scan guarded by deg > SLOT_C.
__global__ void k_gather1(const int* __restrict__ cursor, const int* __restrict__ slots,
                          const int* __restrict__ ovf, const int* __restrict__ ovf_cnt,
                          const float* __restrict__ dinv, const float* __restrict__ x,
                          float* xp, int n) {
    int v = blockIdx.x * blockDim.x + threadIdx.x;
    if (v >= n) return;
    float dv = dinv[v];
    const float4* x4 = (const float4*)x;
    float4 xv = x4[v];
    float sl = dv * dv;
    float4 A = make_float4(sl * xv.x, sl * xv.y, sl * xv.z, sl * xv.w);
    float4 B = make_float4(0.f, 0.f, 0.f, 0.f);
    float4 C = make_float4(0.f, 0.f, 0.f, 0.f);
    float4 D = make_float4(0.f, 0.f, 0.f, 0.f);
    int deg = cursor[v];
    int m = deg < SLOT_C ? deg : SLOT_C;
    const int* sb = slots + v * SLOT_C;
    int e = 0;
    for (; e + 4 <= m; e += 4) {
        int s0 = sb[e], s1 = sb[e + 1], s2 = sb[e + 2], s3 = sb[e + 3];
        float n0 = dinv[s0] * dv, n1 = dinv[s1] * dv;
        float n2 = dinv[s2] * dv, n3 = dinv[s3] * dv;
        float4 r0 = x4[s0], r1 = x4[s1], r2 = x4[s2], r3 = x4[s3];
        A.x = fmaf(n0, r0.x, A.x); A.y = fmaf(n0, r0.y, A.y);
        A.z = fmaf(n0, r0.z, A.z); A.w = fmaf(n0, r0.w, A.w);
        B.x = fmaf(n1, r1.x, B.x); B.y = fmaf(n1, r1.y, B.y);
        B.z = fmaf(n1, r1.z, B.z); B.w = fmaf(n1, r1.w, B.w);
        C.x = fmaf(n2, r2.x, C.x); C.y = fmaf(n2, r2.y, C.y);
        C.z = fmaf(n2, r2.z, C.z); C.w = fmaf(n2, r2.w, C.w);
        D.x = fmaf(n3, r3.x, D.x); D.y = fmaf(n3, r3.y, D.y);
        D.z = fmaf(n3, r3.z, D.z); D.w = fmaf(n3, r3.w, D.w);
    }
    for (; e < m; e++) {
        int s = sb[e];
        float nm = dinv[s] * dv;
        float4 r = x4[s];
        A.x = fmaf(nm, r.x, A.x); A.y = fmaf(nm, r.y, A.y);
        A.z = fmaf(nm, r.z, A.z); A.w = fmaf(nm, r.w, A.w);
    }
    if (deg > SLOT_C) {                  // only truncated nodes scan the list
        int oc = *ovf_cnt;
        for (int k = 0; k < oc; k++) {
            if (ovf[2 * k + 1] == v) {
                int s = ovf[2 * k];
                float nm = dinv[s] * dv;
                float4 r = x4[s];
                A.x = fmaf(nm, r.x, A.x); A.y = fmaf(nm, r.y, A.y);
                A.z = fmaf(nm, r.z, A.z); A.w = fmaf(nm, r.w, A.w);
            }
        }
    }
    float4 o;
    o.x = (A.x + B.x) + (C.x + D.x);
    o.y = (A.y + B.y) + (C.y + D.y);
    o.z = (A.z + B.z) + (C.z + D.z);
    o.w = (A.w + B.w) + (C.w + D.w);
    ((float4*)xp)[v] = o;
}

// K7: f1 = relu(xp @ W1 + b1), output packed bf16 (2 ch per uint).
__global__ void k_f1(const float* __restrict__ xp, const float* __restrict__ W1,
                     const float* __restrict__ b1, unsigned* f1p, int n) {
    int i = blockIdx.x * blockDim.x + threadIdx.x;
    if (i >= n * 64) return;
    int v = i >> 6, cp = i & 63;
    int c0 = cp * 2, c1 = c0 + 1;
    float4 xv = *(const float4*)(xp + v * IN_C);
    float s0 = fmaf(xv.x, W1[c0],
               fmaf(xv.y, W1[HID + c0],
               fmaf(xv.z, W1[2 * HID + c0],
               fmaf(xv.w, W1[3 * HID + c0], b1[c0]))));
    float s1 = fmaf(xv.x, W1[c1],
               fmaf(xv.y, W1[HID + c1],
               fmaf(xv.z, W1[2 * HID + c1],
               fmaf(xv.w, W1[3 * HID + c1], b1[c1]))));
    s0 = s0 > 0.0f ? s0 : 0.0f;
    s1 = s1 > 0.0f ? s1 : 0.0f;
    f1p[i] = f2bf(s0) | (f2bf(s1) << 16);
}

// K8: layer-2 gather (split-wave): lanes 0-31 even edges / 32-63 odd edges,
// uint2 per lane; output acc2 packed bf16. Overflow scan guarded.
__global__ __launch_bounds__(256) void k_gather2(
        const int* __restrict__ cursor, const int* __restrict__ slots,
        const int* __restrict__ ovf, const int* __restrict__ ovf_cnt,
        const float* __restrict__ dinv, const unsigned* __restrict__ f1p,
        unsigned* acc2b, int n) {
    int wv = threadIdx.x >> 6;           // wave id 0..3
    int ln = threadIdx.x & 63;
    int h  = ln >> 5;                    // half = edge parity
    int q  = ln & 31;                    // channel quad: ch 4q..4q+3
    int v = blockIdx.x * 4 + wv;
    if (v >= n) return;
    float dv = dinv[v];
    const uint2* F = (const uint2*)f1p;  // row = 32 uint2

    uint2 us = F[(size_t)v * 32 + q];
    float sl = (h == 0) ? dv * dv : 0.0f;
    float A[4] = { sl * bf_lo(us.x), sl * bf_hi(us.x),
                   sl * bf_lo(us.y), sl * bf_hi(us.y) };
    float B[4] = {0.f, 0.f, 0.f, 0.f};
    float C[4] = {0.f, 0.f, 0.f, 0.f};
    float D[4] = {0.f, 0.f, 0.f, 0.f};

    int deg = cursor[v];
    int m = deg < SLOT_C ? deg : SLOT_C;
    const int* sb = slots + v * SLOT_C;
    int e = 0;
    for (; e + 8 <= m; e += 8) {
        int sA = sb[e + h];
        int sB = sb[e + 2 + h];
        int sC = sb[e + 4 + h];
        int sD = sb[e + 6 + h];
        float nA = dinv[sA] * dv, nB = dinv[sB] * dv;
        float nC = dinv[sC] * dv, nD = dinv[sD] * dv;
        uint2 uA = F[(size_t)sA * 32 + q];
        uint2 uB = F[(size_t)sB * 32 + q];
        uint2 uC = F[(size_t)sC * 32 + q];
        uint2 uD = F[(size_t)sD * 32 + q];
        A[0] = fmaf(nA, bf_lo(uA.x), A[0]); A[1] = fmaf(nA, bf_hi(uA.x), A[1]);
        A[2] = fmaf(nA, bf_lo(uA.y), A[2]); A[3] = fmaf(nA, bf_hi(uA.y), A[3]);
        B[0] = fmaf(nB, bf_lo(uB.x), B[0]); B[1] = fmaf(nB, bf_hi(uB.x), B[1]);
        B[2] = fmaf(nB, bf_lo(uB.y), B[2]); B[3] = fmaf(nB, bf_hi(uB.y), B[3]);
        C[0] = fmaf(nC, bf_lo(uC.x), C[0]); C[1] = fmaf(nC, bf_hi(uC.x), C[1]);
        C[2] = fmaf(nC, bf_lo(uC.y), C[2]); C[3] = fmaf(nC, bf_hi(uC.y), C[3]);
        D[0] = fmaf(nD, bf_lo(uD.x), D[0]); D[1] = fmaf(nD, bf_hi(uD.x), D[1]);
        D[2] = fmaf(nD, bf_lo(uD.y), D[2]); D[3] = fmaf(nD, bf_hi(uD.y), D[3]);
    }
    for (; e + 2 <= m; e += 2) {
        int s = sb[e + h];
        float nm = dinv[s] * dv;
        uint2 u = F[(size_t)s * 32 + q];
        A[0] = fmaf(nm, bf_lo(u.x), A[0]); A[1] = fmaf(nm, bf_hi(u.x), A[1]);
        A[2] = fmaf(nm, bf_lo(u.y), A[2]); A[3] = fmaf(nm, bf_hi(u.y), A[3]);
    }
    if (e < m) {                         // odd tail: half 0 only
        int s = sb[e];
        float nm = (h == 0) ? dinv[s] * dv : 0.0f;
        uint2 u = F[(size_t)s * 32 + q];
        A[0] = fmaf(nm, bf_lo(u.x), A[0]); A[1] = fmaf(nm, bf_hi(u.x), A[1]);
        A[2] = fmaf(nm, bf_lo(u.y), A[2]); A[3] = fmaf(nm, bf_hi(u.y), A[3]);
    }
    if (deg > SLOT_C) {                  // only truncated nodes scan the list
        int oc = *ovf_cnt;
        for (int k = 0; k < oc; k++) {
            if (ovf[2 * k + 1] == v && h == 0) {
                int s = ovf[2 * k];
                float nm = dinv[s] * dv;
                uint2 u = F[(size_t)s * 32 + q];
                A[0] = fmaf(nm, bf_lo(u.x), A[0]); A[1] = fmaf(nm, bf_hi(u.x), A[1]);
                A[2] = fmaf(nm, bf_lo(u.y), A[2]); A[3] = fmaf(nm, bf_hi(u.y), A[3]);
            }
        }
    }

    float o0 = (A[0] + B[0]) + (C[0] + D[0]);
    float o1 = (A[1] + B[1]) + (C[1] + D[1]);
    float o2 = (A[2] + B[2]) + (C[2] + D[2]);
    float o3 = (A[3] + B[3]) + (C[3] + D[3]);
    o0 += __shfl_xor(o0, 32, 64);
    o1 += __shfl_xor(o1, 32, 64);
    o2 += __shfl_xor(o2, 32, 64);
    o3 += __shfl_xor(o3, 32, 64);
    if (h == 0) {
        uint2 w;
        w.x = f2bf(o0) | (f2bf(o1) << 16);
        w.y = f2bf(o2) | (f2bf(o3) << 16);
        ((uint2*)acc2b)[(size_t)v * 32 + q] = w;
    }
}

// K9: MFMA GEMM + fused bias/ReLU/segment-pool.
__global__ __launch_bounds__(256) void k_mm2_pool(
        const unsigned* __restrict__ acc2b, const unsigned short* __restrict__ w2f,
        const float* __restrict__ b2, const int* __restrict__ batch,
        float* out, int n) {
    __shared__ int bch[64];
    int t = threadIdx.x;
    int w = t >> 6, lane = t & 63;
    int quad = lane >> 4, nloc = lane & 15;
    int v0 = blockIdx.x * 64;
    if (t < 64) {
        int v = v0 + t;
        bch[t] = (v < n) ? batch[v] : -1;
    }
    __syncthreads();

    int va = v0 + w * 16 + nloc;
    if (va >= n) va = n - 1;

    const uint4* A4 = (const uint4*)acc2b;      // row = 16 uint4
    const uint4* B4 = (const uint4*)w2f;        // frag blk = 64 uint4

    f32x4 acc[8];
#pragma unroll
    for (int nt = 0; nt < 8; nt++) acc[nt] = (f32x4){0.f, 0.f, 0.f, 0.f};

#pragma unroll
    for (int kk = 0; kk < 4; kk++) {
        FragU af;
        af.u = A4[(size_t)va * 16 + kk * 4 + quad];
#pragma unroll
        for (int nt = 0; nt < 8; nt++) {
            FragU bf;
            bf.u = B4[(kk * 8 + nt) * 64 + lane];
            acc[nt] = __builtin_amdgcn_mfma_f32_16x16x32_bf16(af.b, bf.b, acc[nt], 0, 0, 0);
        }
    }

    int b0 = bch[w * 16], b15 = bch[w * 16 + 15];
    if (b0 == b15 && b0 >= 0) {
#pragma unroll
        for (int nt = 0; nt < 8; nt++) {
            float bias = b2[nt * 16 + nloc];
            float s = 0.f;
#pragma unroll
            for (int reg = 0; reg < 4; reg++) {
                float f = acc[nt][reg] + bias;
                s += f > 0.f ? f : 0.f;
            }
            s += __shfl_xor(s, 16, 64);
            s += __shfl_xor(s, 32, 64);
            if (lane < 16) atomicAdd(&out[b0 * HID + nt * 16 + lane], s);
        }
    } else {
#pragma unroll
        for (int nt = 0; nt < 8; nt++) {
            float bias = b2[nt * 16 + nloc];
            int cur = -1; float run = 0.f;
#pragma unroll
            for (int reg = 0; reg < 4; reg++) {
                int b = bch[w * 16 + quad * 4 + reg];
                if (b < 0) continue;
                float f = acc[nt][reg] + bias;
                f = f > 0.f ? f : 0.f;
                if (b != cur) {
                    if (cur >= 0) atomicAdd(&out[cur * HID + nt * 16 + nloc], run);
                    run = 0.f; cur = b;
                }
                run += f;
            }
            if (cur >= 0) atomicAdd(&out[cur * HID + nt * 16 + nloc], run);
        }
    }
}

// K10: out[b][c] /= max(cnt[b], 1)
__global__ void k_div(float* out, const int* __restrict__ cnt, int outsz) {
    int i = blockIdx.x * blockDim.x + threadIdx.x;
    if (i < outsz) {
        int b = i >> 7;
        float cf = (float)cnt[b];
        out[i] = out[i] / fmaxf(cf, 1.0f);
    }
}

extern "C" void kernel_launch(void* const* d_in, const int* in_sizes, int n_in,
                              void* d_out, int out_size, void* d_ws, size_t ws_size,
                              hipStream_t stream) {
    const float* x   = (const float*)d_in[0];
    const int* ei    = (const int*)d_in[1];   // [2, E] flat: src then dst
    const int* batch = (const int*)d_in[2];
    const float* W1  = (const float*)d_in[3];
    const float* b1  = (const float*)d_in[4];
    const float* W2  = (const float*)d_in[5];
    const float* b2  = (const float*)d_in[6];
    float* out = (float*)d_out;

    int n  = in_sizes[0] / IN_C;
    int e  = in_sizes[1] / 2;
    int bg = out_size / HID;
    const int* src = ei;
    const int* dst = ei + e;

    size_t off_b = 0;
    char* base = (char*)d_ws;
    auto carve = [&](size_t bytes) -> void* {
        void* p = base + off_b;
        off_b += (bytes + 255) & ~(size_t)255;
        return p;
    };
    int*            cursor  = (int*)carve((size_t)n * 4);
    int*            slots   = (int*)carve((size_t)n * SLOT_C * 4);
    int*            ovf     = (int*)carve((size_t)e * 2 * 4);
    int*            ovf_cnt = (int*)carve(256);
    float*          dinv    = (float*)carve((size_t)n * 4);
    float*          xp      = (float*)carve((size_t)n * IN_C * 4);
    unsigned*       f1p     = (unsigned*)carve((size_t)n * 64 * 4);    // bf16-packed
    unsigned*       acc2b   = (unsigned*)carve((size_t)n * 64 * 4);    // bf16-packed
    unsigned short* w2f     = (unsigned short*)carve((size_t)HID * HID * 2);
    int*            cnt     = (int*)carve((size_t)bg * 4);
    (void)ws_size;

    int gN = (n + TPB - 1) / TPB;
    int gE = (e + TPB - 1) / TPB;

    k_prep<<<gN + 64 + 1, TPB, 0, stream>>>(cursor, out, n, out_size, W2, w2f,
                                            batch, cnt, bg, ovf_cnt);
    k_bucket<<<gE * 8, TPB, 0, stream>>>(src, dst, cursor, slots, ovf, ovf_cnt, e, n);
    k_dinv<<<gN, TPB, 0, stream>>>(cursor, dinv, n);
    k_gather1<<<gN, TPB, 0, stream>>>(cursor, slots, ovf, ovf_cnt, dinv, x, xp, n);
    k_f1<<<(n * 64 + TPB - 1) / TPB, TPB, 0, stream>>>(xp, W1, b1, f1p, n);
    k_gather2<<<(n + 3) / 4, 256, 0, stream>>>(cursor, slots, ovf, ovf_cnt, dinv, f1p, acc2b, n);
    k_mm2_pool<<<(n + 63) / 64, 256, 0, stream>>>(acc2b, w2f, b2, batch, out, n);
    k_div<<<(out_size + TPB - 1) / TPB, TPB, 0, stream>>>(out, cnt, out_size);
}

// Round 18
// 272.981 us; speedup vs baseline: 1.0580x; 1.0580x over previous
//
#include <hip/hip_runtime.h>

#define TPB 256
#define HID 128
#define IN_C 4
#define SLOT_C 32          // per-node slot capacity; Poisson(16): P(deg>32)~1e-4,
                           // ~10 overflow nodes @ n=1e5 -> ovf list handles them.

typedef __attribute__((ext_vector_type(8))) short bf16x8;   // 8 bf16 = 4 VGPRs
typedef __attribute__((ext_vector_type(4))) float f32x4;

union FragU { uint4 u; bf16x8 b; };

// bf16 helpers: pack with RNE, unpack with shift (values finite, no NaN)
__device__ __forceinline__ unsigned f2bf(float f) {
    unsigned u = __float_as_uint(f);
    return (u + 0x7fffu + ((u >> 16) & 1u)) >> 16;
}
__device__ __forceinline__ float bf_lo(unsigned u) { return __uint_as_float(u << 16); }
__device__ __forceinline__ float bf_hi(unsigned u) { return __uint_as_float(u & 0xffff0000u); }

// ---------------------------------------------------------------------------
// K0: fused prep — role by blockIdx: [0,nbA) zero cursor/out; [nbA,nbA+64)
// w2frag swizzle; last block: per-graph counts + ovf_cnt=0.
__global__ void k_prep(int* cursor, float* out, int n, int outsz,
                       const float* __restrict__ W2, unsigned short* w2f,
                       const int* __restrict__ batch, int* cnt, int bg,
                       int* ovf_cnt) {
    int nbA = (n + TPB - 1) / TPB;
    int b = blockIdx.x;
    if (b < nbA) {
        int i = b * TPB + threadIdx.x;
        if (i < n) cursor[i] = 0;
        if (i < outsz) out[i] = 0.0f;
    } else if (b < nbA + 64) {
        int i = (b - nbA) * TPB + threadIdx.x;   // 0..16383
        if (i < HID * HID) {
            int j = i & 7, frag = i >> 3;
            int lane = frag & 63, blk = frag >> 6;       // blk = kk*8 + nt
            int kk = blk >> 3, nt = blk & 7;
            int quad = lane >> 4, nloc = lane & 15;
            int k = kk * 32 + quad * 8 + j;
            int c = nt * 16 + nloc;
            w2f[i] = (unsigned short)f2bf(W2[k * HID + c]);
        }
    } else {
        int g = threadIdx.x;
        if (g == 0) *ovf_cnt = 0;
        if (g < bg) {
            int lo0 = 0, hi0 = n;
            while (lo0 < hi0) { int m = (lo0 + hi0) >> 1; if (batch[m] < g) lo0 = m + 1; else hi0 = m; }
            int lo1 = lo0, hi1 = n;
            while (lo1 < hi1) { int m = (lo1 + hi1) >> 1; if (batch[m] < g + 1) lo1 = m + 1; else hi1 = m; }
            cnt[g] = lo1 - lo0;
        }
    }
}

// K1: direct bucket sort, XCD-localized (8 filtered passes). Plain loads
// (R16 config — NT loads traded read latency for write merge, net negative).
__global__ void k_bucket(const int* __restrict__ src, const int* __restrict__ dst,
                         int* cursor, int* slots, int* ovf, int* ovf_cnt,
                         int e, int n) {
    int pass = blockIdx.x & 7;
    int i = (blockIdx.x >> 3) * blockDim.x + threadIdx.x;
    if (i >= e) return;
    int rlo = (int)(((long)n * pass) >> 3);
    int rhi = (int)(((long)n * (pass + 1)) >> 3);
    int d = dst[i];
    if (d >= rlo && d < rhi) {
        int p = atomicAdd(&cursor[d], 1);
        if (p < SLOT_C) {
            slots[d * SLOT_C + p] = src[i];
        } else {                                  // rare (P~1e-4 per node)
            int o = atomicAdd(ovf_cnt, 1);
            ovf[2 * o] = src[i];
            ovf[2 * o + 1] = d;
        }
    }
}

// K2: dinv = rsqrt(deg + 1)  (deg = cursor)
__global__ void k_dinv(const int* __restrict__ cursor, float* dinv, int n) {
    int i = blockIdx.x * blockDim.x + threadIdx.x;
    if (i < n) dinv[i] = rsqrtf((float)cursor[i] + 1.0f);
}

// K6: FUSED layer-1 gather + W1 MLP -> packed bf16 f1p.
// Phase A: thread t gathers node v0+t's 4-ch propagation into LDS (stride 5
// floats, conflict-free). Phase B: thread t owns channel-pair cp=t&63 (its 8
// W1 weights + 2 biases in REGISTERS), loops 64 node-groups with broadcast
// LDS reads and coalesced 256B row writes. Kills the xp round-trip + 1 launch.
__global__ __launch_bounds__(256) void k_g1f1(
        const int* __restrict__ cursor, const int* __restrict__ slots,
        const int* __restrict__ ovf, const int* __restrict__ ovf_cnt,
        const float* __restrict__ dinv, const float* __restrict__ x,
        const float* __restrict__ W1, const float* __restrict__ b1,
        unsigned* f1p, int n) {
    __shared__ float xs[256 * 5];
    int t = threadIdx.x;
    int v0 = blockIdx.x * 256;

    // ---- phase A: gather (one thread per node) ----
    int v = v0 + t;
    if (v < n) {
        float dv = dinv[v];
        const float4* x4 = (const float4*)x;
        float4 xv = x4[v];
        float sl = dv * dv;
        float4 A = make_float4(sl * xv.x, sl * xv.y, sl * xv.z, sl * xv.w);
        float4 B = make_float4(0.f, 0.f, 0.f, 0.f);
        float4 C = make_float4(0.f, 0.f, 0.f, 0.f);
        float4 D = make_float4(0.f, 0.f, 0.f, 0.f);
        int deg = cursor[v];
        int m = deg < SLOT_C ? deg : SLOT_C;
        const int* sb = slots + v * SLOT_C;
        int e = 0;
        for (; e + 4 <= m; e += 4) {
            int s0 = sb[e], s1 = sb[e + 1], s2 = sb[e + 2], s3 = sb[e + 3];
            float n0 = dinv[s0] * dv, n1 = dinv[s1] * dv;
            float n2 = dinv[s2] * dv, n3 = dinv[s3] * dv;
            float4 r0 = x4[s0], r1 = x4[s1], r2 = x4[s2], r3 = x4[s3];
            A.x = fmaf(n0, r0.x, A.x); A.y = fmaf(n0, r0.y, A.y);
            A.z = fmaf(n0, r0.z, A.z); A.w = fmaf(n0, r0.w, A.w);
            B.x = fmaf(n1, r1.x, B.x); B.y = fmaf(n1, r1.y, B.y);
            B.z = fmaf(n1, r1.z, B.z); B.w = fmaf(n1, r1.w, B.w);
            C.x = fmaf(n2, r2.x, C.x); C.y = fmaf(n2, r2.y, C.y);
            C.z = fmaf(n2, r2.z, C.z); C.w = fmaf(n2, r2.w, C.w);
            D.x = fmaf(n3, r3.x, D.x); D.y = fmaf(n3, r3.y, D.y);
            D.z = fmaf(n3, r3.z, D.z); D.w = fmaf(n3, r3.w, D.w);
        }
        for (; e < m; e++) {
            int s = sb[e];
            float nm = dinv[s] * dv;
            float4 r = x4[s];
            A.x = fmaf(nm, r.x, A.x); A.y = fmaf(nm, r.y, A.y);
            A.z = fmaf(nm, r.z, A.z); A.w = fmaf(nm, r.w, A.w);
        }
        if (deg > SLOT_C) {              // only truncated nodes scan the list
            int oc = *ovf_cnt;
            for (int k = 0; k < oc; k++) {
                if (ovf[2 * k + 1] == v) {
                    int s = ovf[2 * k];
                    float nm = dinv[s] * dv;
                    float4 r = x4[s];
                    A.x = fmaf(nm, r.x, A.x); A.y = fmaf(nm, r.y, A.y);
                    A.z = fmaf(nm, r.z, A.z); A.w = fmaf(nm, r.w, A.w);
                }
            }
        }
        xs[t * 5 + 0] = (A.x + B.x) + (C.x + D.x);
        xs[t * 5 + 1] = (A.y + B.y) + (C.y + D.y);
        xs[t * 5 + 2] = (A.z + B.z) + (C.z + D.z);
        xs[t * 5 + 3] = (A.w + B.w) + (C.w + D.w);
    }
    __syncthreads();

    // ---- phase B: W1 MLP + relu + bf16 pack ----
    int cp = t & 63;                     // constant per thread
    int c0 = cp * 2, c1 = c0 + 1;
    float w00 = W1[c0],           w01 = W1[c1];
    float w10 = W1[HID + c0],     w11 = W1[HID + c1];
    float w20 = W1[2 * HID + c0], w21 = W1[2 * HID + c1];
    float w30 = W1[3 * HID + c0], w31 = W1[3 * HID + c1];
    float bb0 = b1[c0],           bb1 = b1[c1];
    int g = t >> 6;                      // node sub-group 0..3 (wave-uniform)
    for (int iter = 0; iter < 64; iter++) {
        int node = iter * 4 + g;
        int vv = v0 + node;
        if (vv >= n) break;              // wave-uniform
        float x0 = xs[node * 5 + 0], x1 = xs[node * 5 + 1];
        float x2 = xs[node * 5 + 2], x3 = xs[node * 5 + 3];
        float s0 = fmaf(x0, w00, fmaf(x1, w10, fmaf(x2, w20, fmaf(x3, w30, bb0))));
        float s1 = fmaf(x0, w01, fmaf(x1, w11, fmaf(x2, w21, fmaf(x3, w31, bb1))));
        s0 = s0 > 0.0f ? s0 : 0.0f;
        s1 = s1 > 0.0f ? s1 : 0.0f;
        f1p[(size_t)vv * 64 + cp] = f2bf(s0) | (f2bf(s1) << 16);
    }
}

// K8: layer-2 gather (split-wave): lanes 0-31 even edges / 32-63 odd edges,
// uint2 per lane; output acc2 packed bf16. Overflow scan guarded.
__global__ __launch_bounds__(256) void k_gather2(
        const int* __restrict__ cursor, const int* __restrict__ slots,
        const int* __restrict__ ovf, const int* __restrict__ ovf_cnt,
        const float* __restrict__ dinv, const unsigned* __restrict__ f1p,
        unsigned* acc2b, int n) {
    int wv = threadIdx.x >> 6;           // wave id 0..3
    int ln = threadIdx.x & 63;
    int h  = ln >> 5;                    // half = edge parity
    int q  = ln & 31;                    // channel quad: ch 4q..4q+3
    int v = blockIdx.x * 4 + wv;
    if (v >= n) return;
    float dv = dinv[v];
    const uint2* F = (const uint2*)f1p;  // row = 32 uint2

    uint2 us = F[(size_t)v * 32 + q];
    float sl = (h == 0) ? dv * dv : 0.0f;
    float A[4] = { sl * bf_lo(us.x), sl * bf_hi(us.x),
                   sl * bf_lo(us.y), sl * bf_hi(us.y) };
    float B[4] = {0.f, 0.f, 0.f, 0.f};
    float C[4] = {0.f, 0.f, 0.f, 0.f};
    float D[4] = {0.f, 0.f, 0.f, 0.f};

    int deg = cursor[v];
    int m = deg < SLOT_C ? deg : SLOT_C;
    const int* sb = slots + v * SLOT_C;
    int e = 0;
    for (; e + 8 <= m; e += 8) {
        int sA = sb[e + h];
        int sB = sb[e + 2 + h];
        int sC = sb[e + 4 + h];
        int sD = sb[e + 6 + h];
        float nA = dinv[sA] * dv, nB = dinv[sB] * dv;
        float nC = dinv[sC] * dv, nD = dinv[sD] * dv;
        uint2 uA = F[(size_t)sA * 32 + q];
        uint2 uB = F[(size_t)sB * 32 + q];
        uint2 uC = F[(size_t)sC * 32 + q];
        uint2 uD = F[(size_t)sD * 32 + q];
        A[0] = fmaf(nA, bf_lo(uA.x), A[0]); A[1] = fmaf(nA, bf_hi(uA.x), A[1]);
        A[2] = fmaf(nA, bf_lo(uA.y), A[2]); A[3] = fmaf(nA, bf_hi(uA.y), A[3]);
        B[0] = fmaf(nB, bf_lo(uB.x), B[0]); B[1] = fmaf(nB, bf_hi(uB.x), B[1]);
        B[2] = fmaf(nB, bf_lo(uB.y), B[2]); B[3] = fmaf(nB, bf_hi(uB.y), B[3]);
        C[0] = fmaf(nC, bf_lo(uC.x), C[0]); C[1] = fmaf(nC, bf_hi(uC.x), C[1]);
        C[2] = fmaf(nC, bf_lo(uC.y), C[2]); C[3] = fmaf(nC, bf_hi(uC.y), C[3]);
        D[0] = fmaf(nD, bf_lo(uD.x), D[0]); D[1] = fmaf(nD, bf_hi(uD.x), D[1]);
        D[2] = fmaf(nD, bf_lo(uD.y), D[2]); D[3] = fmaf(nD, bf_hi(uD.y), D[3]);
    }
    for (; e + 2 <= m; e += 2) {
        int s = sb[e + h];
        float nm = dinv[s] * dv;
        uint2 u = F[(size_t)s * 32 + q];
        A[0] = fmaf(nm, bf_lo(u.x), A[0]); A[1] = fmaf(nm, bf_hi(u.x), A[1]);
        A[2] = fmaf(nm, bf_lo(u.y), A[2]); A[3] = fmaf(nm, bf_hi(u.y), A[3]);
    }
    if (e < m) {                         // odd tail: half 0 only
        int s = sb[e];
        float nm = (h == 0) ? dinv[s] * dv : 0.0f;
        uint2 u = F[(size_t)s * 32 + q];
        A[0] = fmaf(nm, bf_lo(u.x), A[0]); A[1] = fmaf(nm, bf_hi(u.x), A[1]);
        A[2] = fmaf(nm, bf_lo(u.y), A[2]); A[3] = fmaf(nm, bf_hi(u.y), A[3]);
    }
    if (deg > SLOT_C) {                  // only truncated nodes scan the list
        int oc = *ovf_cnt;
        for (int k = 0; k < oc; k++) {
            if (ovf[2 * k + 1] == v && h == 0) {
                int s = ovf[2 * k];
                float nm = dinv[s] * dv;
                uint2 u = F[(size_t)s * 32 + q];
                A[0] = fmaf(nm, bf_lo(u.x), A[0]); A[1] = fmaf(nm, bf_hi(u.x), A[1]);
                A[2] = fmaf(nm, bf_lo(u.y), A[2]); A[3] = fmaf(nm, bf_hi(u.y), A[3]);
            }
        }
    }

    float o0 = (A[0] + B[0]) + (C[0] + D[0]);
    float o1 = (A[1] + B[1]) + (C[1] + D[1]);
    float o2 = (A[2] + B[2]) + (C[2] + D[2]);
    float o3 = (A[3] + B[3]) + (C[3] + D[3]);
    o0 += __shfl_xor(o0, 32, 64);
    o1 += __shfl_xor(o1, 32, 64);
    o2 += __shfl_xor(o2, 32, 64);
    o3 += __shfl_xor(o3, 32, 64);
    if (h == 0) {
        uint2 w;
        w.x = f2bf(o0) | (f2bf(o1) << 16);
        w.y = f2bf(o2) | (f2bf(o3) << 16);
        ((uint2*)acc2b)[(size_t)v * 32 + q] = w;
    }
}

// K9: MFMA GEMM + fused bias/ReLU/segment-pool.
__global__ __launch_bounds__(256) void k_mm2_pool(
        const unsigned* __restrict__ acc2b, const unsigned short* __restrict__ w2f,
        const float* __restrict__ b2, const int* __restrict__ batch,
        float* out, int n) {
    __shared__ int bch[64];
    int t = threadIdx.x;
    int w = t >> 6, lane = t & 63;
    int quad = lane >> 4, nloc = lane & 15;
    int v0 = blockIdx.x * 64;
    if (t < 64) {
        int v = v0 + t;
        bch[t] = (v < n) ? batch[v] : -1;
    }
    __syncthreads();

    int va = v0 + w * 16 + nloc;
    if (va >= n) va = n - 1;

    const uint4* A4 = (const uint4*)acc2b;      // row = 16 uint4
    const uint4* B4 = (const uint4*)w2f;        // frag blk = 64 uint4

    f32x4 acc[8];
#pragma unroll
    for (int nt = 0; nt < 8; nt++) acc[nt] = (f32x4){0.f, 0.f, 0.f, 0.f};

#pragma unroll
    for (int kk = 0; kk < 4; kk++) {
        FragU af;
        af.u = A4[(size_t)va * 16 + kk * 4 + quad];
#pragma unroll
        for (int nt = 0; nt < 8; nt++) {
            FragU bf;
            bf.u = B4[(kk * 8 + nt) * 64 + lane];
            acc[nt] = __builtin_amdgcn_mfma_f32_16x16x32_bf16(af.b, bf.b, acc[nt], 0, 0, 0);
        }
    }

    int b0 = bch[w * 16], b15 = bch[w * 16 + 15];
    if (b0 == b15 && b0 >= 0) {
#pragma unroll
        for (int nt = 0; nt < 8; nt++) {
            float bias = b2[nt * 16 + nloc];
            float s = 0.f;
#pragma unroll
            for (int reg = 0; reg < 4; reg++) {
                float f = acc[nt][reg] + bias;
                s += f > 0.f ? f : 0.f;
            }
            s += __shfl_xor(s, 16, 64);
            s += __shfl_xor(s, 32, 64);
            if (lane < 16) atomicAdd(&out[b0 * HID + nt * 16 + lane], s);
        }
    } else {
#pragma unroll
        for (int nt = 0; nt < 8; nt++) {
            float bias = b2[nt * 16 + nloc];
            int cur = -1; float run = 0.f;
#pragma unroll
            for (int reg = 0; reg < 4; reg++) {
                int b = bch[w * 16 + quad * 4 + reg];
                if (b < 0) continue;
                float f = acc[nt][reg] + bias;
                f = f > 0.f ? f : 0.f;
                if (b != cur) {
                    if (cur >= 0) atomicAdd(&out[cur * HID + nt * 16 + nloc], run);
                    run = 0.f; cur = b;
                }
                run += f;
            }
            if (cur >= 0) atomicAdd(&out[cur * HID + nt * 16 + nloc], run);
        }
    }
}

// K10: out[b][c] /= max(cnt[b], 1)
__global__ void k_div(float* out, const int* __restrict__ cnt, int outsz) {
    int i = blockIdx.x * blockDim.x + threadIdx.x;
    if (i < outsz) {
        int b = i >> 7;
        float cf = (float)cnt[b];
        out[i] = out[i] / fmaxf(cf, 1.0f);
    }
}

extern "C" void kernel_launch(void* const* d_in, const int* in_sizes, int n_in,
                              void* d_out, int out_size, void* d_ws, size_t ws_size,
                              hipStream_t stream) {
    const float* x   = (const float*)d_in[0];
    const int* ei    = (const int*)d_in[1];   // [2, E] flat: src then dst
    const int* batch = (const int*)d_in[2];
    const float* W1  = (const float*)d_in[3];
    const float* b1  = (const float*)d_in[4];
    const float* W2  = (const float*)d_in[5];
    const float* b2  = (const float*)d_in[6];
    float* out = (float*)d_out;

    int n  = in_sizes[0] / IN_C;
    int e  = in_sizes[1] / 2;
    int bg = out_size / HID;
    const int* src = ei;
    const int* dst = ei + e;

    size_t off_b = 0;
    char* base = (char*)d_ws;
    auto carve = [&](size_t bytes) -> void* {
        void* p = base + off_b;
        off_b += (bytes + 255) & ~(size_t)255;
        return p;
    };
    int*            cursor  = (int*)carve((size_t)n * 4);
    int*            slots   = (int*)carve((size_t)n * SLOT_C * 4);
    int*            ovf     = (int*)carve((size_t)e * 2 * 4);
    int*            ovf_cnt = (int*)carve(256);
    float*          dinv    = (float*)carve((size_t)n * 4);
    unsigned*       f1p     = (unsigned*)carve((size_t)n * 64 * 4);    // bf16-packed
    unsigned*       acc2b   = (unsigned*)carve((size_t)n * 64 * 4);    // bf16-packed
    unsigned short* w2f     = (unsigned short*)carve((size_t)HID * HID * 2);
    int*            cnt     = (int*)carve((size_t)bg * 4);
    (void)ws_size;

    int gN = (n + TPB - 1) / TPB;
    int gE = (e + TPB - 1) / TPB;

    k_prep<<<gN + 64 + 1, TPB, 0, stream>>>(cursor, out, n, out_size, W2, w2f,
                                            batch, cnt, bg, ovf_cnt);
    k_bucket<<<gE * 8, TPB, 0, stream>>>(src, dst, cursor, slots, ovf, ovf_cnt, e, n);
    k_dinv<<<gN, TPB, 0, stream>>>(cursor, dinv, n);
    k_g1f1<<<gN, TPB, 0, stream>>>(cursor, slots, ovf, ovf_cnt, dinv, x, W1, b1, f1p, n);
    k_gather2<<<(n + 3) / 4, 256, 0, stream>>>(cursor, slots, ovf, ovf_cnt, dinv, f1p, acc2b, n);
    k_mm2_pool<<<(n + 63) / 64, 256, 0, stream>>>(acc2b, w2f, b2, batch, out, n);
    k_div<<<(out_size + TPB - 1) / TPB, TPB, 0, stream>>>(out, cnt, out_size);
}